// Round 6
// baseline (122.604 us; speedup 1.0000x reference)
//
#include <hip/hip_runtime.h>
#include <math.h>

#define B 32768
#define S 256
#define H1 10
#define H2 6
#define ROWS 512                 // batch rows per wave
#define CH (B / ROWS)            // 64 chunks per subnet
#define WPB 2                    // waves per block (128 threads)
#define L2_SMOOTH 1e-3f
#define EPS 1e-10f

#define LSC 2.8853900817779268f  // 2*log2(e): prescale so exp2(a_s) = e^{2a}
#define C2L 0.6931471805599453f  // 2/LSC = ln 2
#define RLS 0.34657359027997264f // 1/LSC

typedef __attribute__((ext_vector_type(2))) float v2f;

__device__ __forceinline__ int rfl_i(int x) { return __builtin_amdgcn_readfirstlane(x); }
__device__ __forceinline__ float rfl(float x) {
    return __int_as_float(__builtin_amdgcn_readfirstlane(__float_as_int(x)));
}

// tanh + sech^2 from PRE-SCALED arg a_s = LSC*a (so exp2(a_s) = e^{2a}):
//   r = 1/(e+1); tanh = 1-2r; sech^2 = 4r(1-r). Saturation exact via rcp(inf)=0.
__device__ __forceinline__ void tanh_pair_s(float a_s, float& th, float& s2) {
    const float e = __builtin_amdgcn_exp2f(a_s);
    const float r = __builtin_amdgcn_rcpf(e + 1.0f);
    th = fmaf(-2.0f, r, 1.0f);
    s2 = (4.0f * r) * (1.0f - r);
}

// K1: wave = one subnet, lane = batch row (2 rows/iter). Weights wave-uniform.
// W2 packed over j-pairs as v2f -> v_pk_fma_f32 (packed FP32) for the matvec bulk.
__global__ __launch_bounds__(128, 2) void k1_mlp(
    const float* __restrict__ x,
    const float* __restrict__ W1, const float* __restrict__ b1,
    const float* __restrict__ W2, const float* __restrict__ b2,
    const float* __restrict__ W3, const float* __restrict__ b3,
    float* __restrict__ out,          // [B][S] unnormalized (d_out)
    float* __restrict__ psum,         // [S][CH]
    float* __restrict__ psum2,        // [S][CH]
    float* __restrict__ pg2)          // [S][CH]
{
    const int t   = threadIdx.x;
    const int wid = blockIdx.x * WPB + rfl_i(t >> 6);
    const int l   = t & 63;
    const int s   = wid & (S - 1);    // subnet
    const int c   = wid >> 8;         // batch chunk 0..CH-1

    // ---- wave-uniform parameters (scalarized); scaled variants folded once ----
    float w1[H1], w1e[H1], b1e[H1], m2w1[H1];
#pragma unroll
    for (int i = 0; i < H1; ++i) {
        const float w = rfl(W1[s * H1 + i]);
        w1[i]   = w;
        w1e[i]  = w * LSC;
        m2w1[i] = -2.0f * w * w;
        b1e[i]  = rfl(b1[s * H1 + i]) * LSC;
        asm("" : "+v"(b1e[i]));       // VGPR: partner of SGPR w1e in one fma
    }
    v2f w2p[H1][3];                    // L-scaled, j-pair packed (uniform pairs)
#pragma unroll
    for (int i = 0; i < H1; ++i)
#pragma unroll
        for (int jp = 0; jp < 3; ++jp) {
            w2p[i][jp].x = rfl(W2[(s * H1 + i) * H2 + 2 * jp    ]) * LSC;
            w2p[i][jp].y = rfl(W2[(s * H1 + i) * H2 + 2 * jp + 1]) * LSC;
        }
    v2f b2p[3];
#pragma unroll
    for (int jp = 0; jp < 3; ++jp) {
        b2p[jp].x = rfl(b2[s * H2 + 2 * jp    ]) * LSC;
        b2p[jp].y = rfl(b2[s * H2 + 2 * jp + 1]) * LSC;
    }
    float w3s[H2], w3g[H2];
#pragma unroll
    for (int j = 0; j < H2; ++j) {
        const float w = rfl(W3[s * H2 + j]);
        w3s[j] = w;
        w3g[j] = w * RLS;             // w3/L for the g2 accumulation
    }
    float bb3 = b3[s];
    asm("" : "+v"(bb3));

    const size_t base = (size_t)(c * ROWS) * S + s + (size_t)l * S;
    const float* px = x   + base;
    float*       po = out + base;

    float so = 0.0f, so2 = 0.0f, sg2 = 0.0f;

#pragma unroll 1
    for (int k = 0; k < ROWS / 128; ++k) {      // 2 rows per lane per iter
        const float xA = px[(size_t)(k * 128)      * S];
        const float xB = px[(size_t)(k * 128 + 64) * S];

        v2f vA[3], vpA[3], vppA[3], vB[3], vpB[3], vppB[3];

        float hA, tA, hB, tB;
        {   // i = 0 peeled: pk-fma init against b2p
            tanh_pair_s(fmaf(xA, w1e[0], b1e[0]), hA, tA);
            tanh_pair_s(fmaf(xB, w1e[0], b1e[0]), hB, tB);
            const float hpA = tA * w1[0], hppA = (hA * hpA) * m2w1[0];
            const float hpB = tB * w1[0], hppB = (hB * hpB) * m2w1[0];
#pragma unroll
            for (int jp = 0; jp < 3; ++jp) {
                vA[jp]   = hA   * w2p[0][jp] + b2p[jp];
                vpA[jp]  = hpA  * w2p[0][jp];
                vppA[jp] = hppA * w2p[0][jp];
                vB[jp]   = hB   * w2p[0][jp] + b2p[jp];
                vpB[jp]  = hpB  * w2p[0][jp];
                vppB[jp] = hppB * w2p[0][jp];
            }
        }
#pragma unroll
        for (int i = 1; i < H1; ++i) {
            tanh_pair_s(fmaf(xA, w1e[i], b1e[i]), hA, tA);
            tanh_pair_s(fmaf(xB, w1e[i], b1e[i]), hB, tB);
            const float hpA = tA * w1[i], hppA = (hA * hpA) * m2w1[i];
            const float hpB = tB * w1[i], hppB = (hB * hpB) * m2w1[i];
#pragma unroll
            for (int jp = 0; jp < 3; ++jp) {
                vA[jp]   = hA   * w2p[i][jp] + vA[jp];    // v_pk_fma_f32
                vpA[jp]  = hpA  * w2p[i][jp] + vpA[jp];
                vppA[jp] = hppA * w2p[i][jp] + vppA[jp];
                vB[jp]   = hB   * w2p[i][jp] + vB[jp];
                vpB[jp]  = hpB  * w2p[i][jp] + vpB[jp];
                vppB[jp] = hppB * w2p[i][jp] + vppB[jp];
            }
        }

        float oA = bb3, g2A = 0.0f, oB = bb3, g2B = 0.0f;
#pragma unroll
        for (int jp = 0; jp < 3; ++jp) {
            {   float g, tg; tanh_pair_s(vA[jp].x, g, tg);
                const float q = g * vpA[jp].x, cc = -C2L * q;
                const float gpp = tg * fmaf(cc, vpA[jp].x, vppA[jp].x);
                oA = fmaf(g, w3s[2*jp], oA); g2A = fmaf(w3g[2*jp], gpp, g2A); }
            {   float g, tg; tanh_pair_s(vA[jp].y, g, tg);
                const float q = g * vpA[jp].y, cc = -C2L * q;
                const float gpp = tg * fmaf(cc, vpA[jp].y, vppA[jp].y);
                oA = fmaf(g, w3s[2*jp+1], oA); g2A = fmaf(w3g[2*jp+1], gpp, g2A); }
            {   float g, tg; tanh_pair_s(vB[jp].x, g, tg);
                const float q = g * vpB[jp].x, cc = -C2L * q;
                const float gpp = tg * fmaf(cc, vpB[jp].x, vppB[jp].x);
                oB = fmaf(g, w3s[2*jp], oB); g2B = fmaf(w3g[2*jp], gpp, g2B); }
            {   float g, tg; tanh_pair_s(vB[jp].y, g, tg);
                const float q = g * vpB[jp].y, cc = -C2L * q;
                const float gpp = tg * fmaf(cc, vpB[jp].y, vppB[jp].y);
                oB = fmaf(g, w3s[2*jp+1], oB); g2B = fmaf(w3g[2*jp+1], gpp, g2B); }
        }

        po[(size_t)(k * 128)      * S] = oA;
        po[(size_t)(k * 128 + 64) * S] = oB;
        so += oA; so2 = fmaf(oA, oA, so2); sg2 = fmaf(g2A, g2A, sg2);
        so += oB; so2 = fmaf(oB, oB, so2); sg2 = fmaf(g2B, g2B, sg2);
    }

    // deterministic in-wave butterfly reduction
#pragma unroll
    for (int m = 1; m < 64; m <<= 1) {
        so  += __shfl_xor(so,  m, 64);
        so2 += __shfl_xor(so2, m, 64);
        sg2 += __shfl_xor(sg2, m, 64);
    }
    if (l == 0) {
        psum [s * CH + c] = so;
        psum2[s * CH + c] = so2;
        pg2  [s * CH + c] = sg2;
    }
}

// K2: one wave per subnet reduces CH=64 partials -> mean, 1/std, smooth term
__global__ __launch_bounds__(64) void k2_reduce(
    const float* __restrict__ psum, const float* __restrict__ psum2,
    const float* __restrict__ pg2,
    float* __restrict__ mean_arr, float* __restrict__ rstd_arr,
    float* __restrict__ smooth_arr)
{
    const int s = blockIdx.x;
    const int l = threadIdx.x;       // 0..63 == CH

    float a  = psum [s * CH + l];
    float b_ = psum2[s * CH + l];
    float cc = pg2  [s * CH + l];
#pragma unroll
    for (int m = 1; m < 64; m <<= 1) {
        a  += __shfl_xor(a,  m, 64);
        b_ += __shfl_xor(b_, m, 64);
        cc += __shfl_xor(cc, m, 64);
    }
    if (l == 0) {
        const float inv_b = 1.0f / (float)B;
        const float mean  = a * inv_b;
        float var = b_ * inv_b - mean * mean;
        var = fmaxf(var, 0.0f);
        const float stdv = fmaxf(sqrtf(var), EPS);
        const float rstd = 1.0f / stdv;
        mean_arr[s]   = mean;
        rstd_arr[s]   = rstd;
        smooth_arr[s] = (cc * inv_b) * rstd;   // mean(g2^2)/std
    }
}

// K3: normalize d_out in place (float4), plus one block for the loss sum
#define K3_NORM_BLOCKS (B * S / (256 * 4))   // 8192
__global__ __launch_bounds__(256) void k3_norm(
    float* __restrict__ out,
    const float* __restrict__ mean_arr, const float* __restrict__ rstd_arr,
    const float* __restrict__ smooth_arr)
{
    if ((int)blockIdx.x == K3_NORM_BLOCKS) {
        const int t = threadIdx.x;
        __shared__ float sa[256];
        sa[t] = smooth_arr[t];
        __syncthreads();
        for (int st = 128; st > 0; st >>= 1) {
            if (t < st) sa[t] += sa[t + st];
            __syncthreads();
        }
        if (t == 0) out[B * S] = L2_SMOOTH * sa[0];
        return;
    }

    const int i4   = (int)blockIdx.x * 256 + (int)threadIdx.x;
    const int base = i4 * 4;
    float4 v = *reinterpret_cast<float4*>(&out[base]);
    const int s0 = base & (S - 1);
    v.x = (v.x - mean_arr[s0 + 0]) * rstd_arr[s0 + 0];
    v.y = (v.y - mean_arr[s0 + 1]) * rstd_arr[s0 + 1];
    v.z = (v.z - mean_arr[s0 + 2]) * rstd_arr[s0 + 2];
    v.w = (v.w - mean_arr[s0 + 3]) * rstd_arr[s0 + 3];
    *reinterpret_cast<float4*>(&out[base]) = v;
}

extern "C" void kernel_launch(void* const* d_in, const int* in_sizes, int n_in,
                              void* d_out, int out_size, void* d_ws, size_t ws_size,
                              hipStream_t stream) {
    const float* x  = (const float*)d_in[0];
    const float* W1 = (const float*)d_in[1];
    const float* b1 = (const float*)d_in[2];
    const float* W2 = (const float*)d_in[3];
    const float* b2 = (const float*)d_in[4];
    const float* W3 = (const float*)d_in[5];
    const float* b3 = (const float*)d_in[6];
    float* out = (float*)d_out;

    // ws (floats): psum[S*CH] | psum2[S*CH] | pg2[S*CH] | mean[S] | rstd[S] | smooth[S]
    float* psum   = (float*)d_ws;
    float* psum2  = psum  + S * CH;
    float* pg2    = psum2 + S * CH;
    float* meanA  = pg2   + S * CH;
    float* rstdA  = meanA + S;
    float* smooth = rstdA + S;

    k1_mlp<<<S * CH / WPB, 64 * WPB, 0, stream>>>(
        x, W1, b1, W2, b2, W3, b3, out, psum, psum2, pg2);
    k2_reduce<<<S, 64, 0, stream>>>(psum, psum2, pg2, meanA, rstdA, smooth);
    k3_norm<<<K3_NORM_BLOCKS + 1, 256, 0, stream>>>(out, meanA, rstdA, smooth);
}